// Round 15
// baseline (462.017 us; speedup 1.0000x reference)
//
#include <hip/hip_runtime.h>

#define FEAT 128
#define YS 8.0f     // fp8 encode scale for y = dsq*X
#define YIS 0.125f  // 1/YS
#define BSHIFT 8    // 256 nodes per bucket
#define NBMAX 512
#define BIN_CH 8192
#define CAP 16384   // edges per bucket: mean ~8184 + pad ~1920, 6-sigma safe

typedef __attribute__((ext_vector_type(8))) short bf16x8;
typedef __attribute__((ext_vector_type(4))) float f32x4;
typedef __attribute__((ext_vector_type(4))) int i32x4;
typedef __attribute__((ext_vector_type(2))) float f32x2;

__device__ __forceinline__ float2 upk_bf2(unsigned int p) {
    union { unsigned int u; float f; } a, b;
    a.u = p << 16;
    b.u = p & 0xffff0000u;
    return make_float2(a.f, b.f);
}
__device__ __forceinline__ unsigned short f2bf(float f) {
    union { float f; unsigned int u; } v;
    v.f = f;
    unsigned int b = v.u + 0x7fffu + ((v.u >> 16) & 1u);
    return (unsigned short)(b >> 16);
}
__device__ __forceinline__ unsigned int pk_bf2(float x, float y) {
    return (unsigned int)f2bf(x) | ((unsigned int)f2bf(y) << 16);
}

// ---- Phase A: bin edges by dst bucket into fixed-capacity regions --------
__global__ __launch_bounds__(1024) void bin_kernel(const int* __restrict__ src,
                                                   const int* __restrict__ dst,
                                                   int* __restrict__ bcnt,
                                                   unsigned int* __restrict__ tmp,
                                                   int E, int NB) {
    __shared__ int cnt[NBMAX];
    __shared__ int base[NBMAX];
    int t = threadIdx.x;
    for (int i = t; i < NB; i += 1024) cnt[i] = 0;
    __syncthreads();
    int start = blockIdx.x * BIN_CH;
    int n = E - start;
    if (n > BIN_CH) n = BIN_CH;
    for (int k = t; k < n; k += 1024) atomicAdd(&cnt[dst[start + k] >> BSHIFT], 1);
    __syncthreads();
    for (int i = t; i < NB; i += 1024) {
        int c = cnt[i];
        base[i] = c ? atomicAdd(&bcnt[i], c) : 0;
        cnt[i] = 0;
    }
    __syncthreads();
    for (int k = t; k < n; k += 1024) {
        int s = src[start + k], d = dst[start + k];
        int b = d >> BSHIFT;
        int off = atomicAdd(&cnt[b], 1);
        __builtin_nontemporal_store(((unsigned int)(d & 255) << 24) | (unsigned int)s,
                                    tmp + (size_t)b * CAP + base[b] + off);
    }
}

// ---- Phase B: per-bucket LDS degree count + scan + scatter ---------------
// Pads each node's edge list to a multiple of 16 with sentinel src = N.
__global__ __launch_bounds__(256) void bucket_kernel(
    const unsigned int* __restrict__ tmp, const int* __restrict__ bcnt,
    float* __restrict__ dsq, int* __restrict__ rstart, int* __restrict__ rend,
    int* __restrict__ ssrc, int N) {
    __shared__ int ldeg[256];
    __shared__ int lofs[256];
    int b = blockIdx.x;
    int t = threadIdx.x;
    int cnt = bcnt[b];
    ldeg[t] = 0;
    __syncthreads();
    const unsigned int* tp = tmp + (size_t)b * CAP;
    for (int e = t; e < cnt; e += 256) atomicAdd(&ldeg[tp[e] >> 24], 1);
    __syncthreads();
    int node = (b << BSHIFT) + t;
    int v = 0, pv = 0;
    if (node < N) {
        v = ldeg[t];
        pv = (v + 15) & ~15;
    }
    lofs[t] = pv;
    __syncthreads();
    for (int off = 1; off < 256; off <<= 1) {
        int add = (t >= off) ? lofs[t - off] : 0;
        __syncthreads();
        lofs[t] += add;
        __syncthreads();
    }
    int myStart = lofs[t] - pv;
    if (node < N) {
        dsq[node] = rsqrtf((float)(v < 1 ? 1 : v));
        rstart[node] = b * CAP + myStart;
        rend[node] = b * CAP + lofs[t];
    }
    ldeg[t] = myStart;
    __syncthreads();
    int* sp = ssrc + (size_t)b * CAP;
    for (int e = t; e < cnt; e += 256) {
        unsigned int p = tp[e];
        int dl = p >> 24;
        int pos = atomicAdd(&ldeg[dl], 1);
        sp[pos] = (int)(p & 0xFFFFFFu);
    }
    __syncthreads();
    if (node < N) {
        for (int p = myStart + v; p < myStart + pv; p++) sp[p] = N;
    }
}

// ---- prep: X0b = bf16(signal), y0 = fp8(YS * dsq * signal) --------------
__global__ void prep_kernel(const float* __restrict__ signal, const float* __restrict__ dsq,
                            unsigned int* __restrict__ X0b, unsigned short* __restrict__ y0,
                            unsigned short* __restrict__ y1, int total /* N*64 */) {
    int t = blockIdx.x * blockDim.x + threadIdx.x;
    if (t < 64) {
        y0[total + t] = 0;
        y1[total + t] = 0;
    }
    if (t >= total) return;
    int node = t >> 6;
    f32x2 v = __builtin_nontemporal_load((const f32x2*)signal + t);
    float ds = dsq[node];
    __builtin_nontemporal_store(pk_bf2(v[0], v[1]), X0b + t);
    int p = __builtin_amdgcn_cvt_pk_fp8_f32(v[0] * ds * YS, v[1] * ds * YS, 0, false);
    y0[t] = (unsigned short)p;
}

// ---- W -> fragment-major bf16 layout (1 KB burst per GEMM B-load) --------
__global__ void wconv_kernel(const float* __restrict__ W, unsigned int* __restrict__ Wb2,
                             int total /* 32768 */) {
    int u = blockIdx.x * blockDim.x + threadIdx.x;
    if (u >= total) return;
    int e2 = u & 3;
    int l15 = (u >> 2) & 15;
    int kg = (u >> 6) & 3;
    int kq = (u >> 8) & 3;
    int chunk = (u >> 10) & 3;
    int nt = (u >> 12) & 7;
    int col = nt * 16 + l15;
    int k = chunk * 128 + kq * 32 + kg * 8 + e2 * 2;
    float2 v = ((const float2*)W)[col * 256 + (k >> 1)];
    Wb2[u] = pk_bf2(v.x, v.y);
}

// ---- Fused pull + Chebyshev combine (fp8 gather, bf16 state) -------------
// Round-12 structure (1 node/wave, unroll-16) + NT hints on streams so L2
// retains the y8 gather target.
__global__ __launch_bounds__(256) void pull_combine_kernel(
    const unsigned short* __restrict__ y8, const int* __restrict__ rstart,
    const int* __restrict__ rend, const int* __restrict__ ssrc,
    const float* __restrict__ dsq, const unsigned int* __restrict__ xprev,
    const unsigned int* __restrict__ xpp, const float* __restrict__ lam,
    unsigned int* __restrict__ Xout, unsigned short* __restrict__ yout,
    int N, int mode) {
    int node = (blockIdx.x << 2) + (threadIdx.x >> 6);
    if (node >= N) return;
    int lane = threadIdx.x & 63;
    int i = __builtin_amdgcn_readfirstlane(rstart[node]);
    int end = __builtin_amdgcn_readfirstlane(rend[node]);
    float ax = 0.f, ay = 0.f;
    for (; i < end; i += 16) {
        i32x4 sa = __builtin_nontemporal_load((const i32x4*)(ssrc + i));
        i32x4 sb = __builtin_nontemporal_load((const i32x4*)(ssrc + i + 4));
        i32x4 sc = __builtin_nontemporal_load((const i32x4*)(ssrc + i + 8));
        i32x4 sd = __builtin_nontemporal_load((const i32x4*)(ssrc + i + 12));
        int s[16];
        s[0] = __builtin_amdgcn_readfirstlane(sa[0]);
        s[1] = __builtin_amdgcn_readfirstlane(sa[1]);
        s[2] = __builtin_amdgcn_readfirstlane(sa[2]);
        s[3] = __builtin_amdgcn_readfirstlane(sa[3]);
        s[4] = __builtin_amdgcn_readfirstlane(sb[0]);
        s[5] = __builtin_amdgcn_readfirstlane(sb[1]);
        s[6] = __builtin_amdgcn_readfirstlane(sb[2]);
        s[7] = __builtin_amdgcn_readfirstlane(sb[3]);
        s[8] = __builtin_amdgcn_readfirstlane(sc[0]);
        s[9] = __builtin_amdgcn_readfirstlane(sc[1]);
        s[10] = __builtin_amdgcn_readfirstlane(sc[2]);
        s[11] = __builtin_amdgcn_readfirstlane(sc[3]);
        s[12] = __builtin_amdgcn_readfirstlane(sd[0]);
        s[13] = __builtin_amdgcn_readfirstlane(sd[1]);
        s[14] = __builtin_amdgcn_readfirstlane(sd[2]);
        s[15] = __builtin_amdgcn_readfirstlane(sd[3]);
        unsigned int u[16];
#pragma unroll
        for (int j = 0; j < 16; j++) u[j] = y8[(size_t)s[j] * 64 + lane];
#pragma unroll
        for (int j = 0; j < 16; j++) {
            auto f = __builtin_amdgcn_cvt_pk_f32_fp8((int)u[j], false);
            ax += f[0];
            ay += f[1];
        }
    }
    float r = 2.0f / lam[0];
    float ds = dsq[node];
    size_t idx = (size_t)node * 64 + lane;
    float2 xp = upk_bf2(__builtin_nontemporal_load(xprev + idx));
    float rx, ry;
    if (mode == 1) {
        float alpha = -r * ds * YIS, beta = r - 1.0f;
        rx = alpha * ax + beta * xp.x;
        ry = alpha * ay + beta * xp.y;
    } else {
        float alpha = -2.0f * r * ds * YIS, beta = 2.0f * (r - 1.0f);
        float2 xq = upk_bf2(__builtin_nontemporal_load(xpp + idx));
        rx = alpha * ax + beta * xp.x - xq.x;
        ry = alpha * ay + beta * xp.y - xq.y;
    }
    __builtin_nontemporal_store(pk_bf2(rx, ry), Xout + idx);
    if (yout) {
        int p = __builtin_amdgcn_cvt_pk_fp8_f32(rx * ds * YS, ry * ds * YS, 0, false);
        __builtin_nontemporal_store((unsigned short)p, yout + idx);
    }
}

// ---- MFMA bf16 epilogue GEMM (fragment-major B, NT A-stream) -------------
__global__ __launch_bounds__(256, 4) void mfma_gemm_kernel(
    const unsigned short* __restrict__ X0, const unsigned short* __restrict__ X1,
    const unsigned short* __restrict__ X2, const unsigned short* __restrict__ X3,
    const unsigned short* __restrict__ Wb2, const float* __restrict__ bias,
    float* __restrict__ out, int M) {
    int tid = threadIdx.x;
    int lane = tid & 63;
    int w = tid >> 6;
    int m0 = blockIdx.x * 128 + w * 32;
    int l15 = lane & 15;
    int kg = lane >> 4;

    f32x4 acc[2][8];
#pragma unroll
    for (int rg = 0; rg < 2; rg++)
#pragma unroll
        for (int nt = 0; nt < 8; nt++) acc[rg][nt] = (f32x4)(0.f);

    const unsigned short* Xs[4] = {X0, X1, X2, X3};
    int arow[2];
#pragma unroll
    for (int rg = 0; rg < 2; rg++) {
        int r = m0 + rg * 16 + l15;
        arow[rg] = r < M ? r : M - 1;
    }
    const unsigned short* wlane = Wb2 + (kg * 16 + l15) * 8;

#pragma unroll
    for (int chunk = 0; chunk < 4; ++chunk) {
        const unsigned short* A = Xs[chunk];
#pragma unroll
        for (int kq = 0; kq < 4; kq++) {
            bf16x8 af[2];
#pragma unroll
            for (int rg = 0; rg < 2; rg++)
                af[rg] = __builtin_nontemporal_load(
                    (const bf16x8*)(A + (size_t)arow[rg] * 128 + kq * 32 + kg * 8));
#pragma unroll
            for (int nt = 0; nt < 8; nt++) {
                bf16x8 bf = *(const bf16x8*)(wlane + nt * 8192 + chunk * 2048 + kq * 512);
#pragma unroll
                for (int rg = 0; rg < 2; rg++)
                    acc[rg][nt] = __builtin_amdgcn_mfma_f32_16x16x32_bf16(af[rg], bf,
                                                                          acc[rg][nt], 0, 0, 0);
            }
        }
    }
#pragma unroll
    for (int nt = 0; nt < 8; nt++) {
        int col = nt * 16 + l15;
        float bb = bias[col];
#pragma unroll
        for (int rg = 0; rg < 2; rg++) {
#pragma unroll
            for (int r = 0; r < 4; r++) {
                int row = m0 + rg * 16 + kg * 4 + r;
                if (row < M)
                    __builtin_nontemporal_store(acc[rg][nt][r] + bb,
                                                out + (size_t)row * 128 + col);
            }
        }
    }
}

extern "C" void kernel_launch(void* const* d_in, const int* in_sizes, int n_in,
                              void* d_out, int out_size, void* d_ws, size_t ws_size,
                              hipStream_t stream) {
    const float* signal = (const float*)d_in[0];
    const int* src = (const int*)d_in[1];
    const int* dst = (const int*)d_in[2];
    const float* W = (const float*)d_in[3];
    const float* bias = (const float*)d_in[4];
    const float* lam = (const float*)d_in[5];
    int N = in_sizes[0] / FEAT;
    int E = in_sizes[1];
    float* out = (float*)d_out;
    int NB = (N + (1 << BSHIFT) - 1) >> BSHIFT;

    char* ws = (char*)d_ws;
    size_t off = 0;
    auto alloc = [&](size_t bytes) {
        char* p = ws + off;
        off += (bytes + 511) & ~(size_t)511;
        return p;
    };
    size_t nodeBf = (size_t)N * FEAT * 2;
    size_t nodeF8 = (size_t)(N + 1) * FEAT;
    size_t bucketBytes = (size_t)NB * CAP * 4;

    float* dsq = (float*)alloc((size_t)N * 4);
    int* bcnt = (int*)alloc((size_t)NB * 4);
    int* rstart = (int*)alloc((size_t)N * 4);
    int* rend = (int*)alloc((size_t)N * 4);
    int* ssrc = (int*)alloc(bucketBytes);
    unsigned int* tmp = (unsigned int*)alloc(bucketBytes);  // dead after bucket_kernel
    unsigned int* Wb = (unsigned int*)alloc((size_t)128 * 512 * 2);
    unsigned int* X0b = (unsigned int*)alloc(nodeBf);
    unsigned int* X1b = (unsigned int*)alloc(nodeBf);
    unsigned int* X2b = (unsigned int*)alloc(nodeBf);
    unsigned short* yA = (unsigned short*)alloc(nodeF8);
    unsigned short* yB = (unsigned short*)alloc(nodeF8);
    unsigned int* X3b = tmp;  // overlay: X3 written only after tmp is consumed

    // CSR build (bucket-local, no global node-granularity atomics)
    hipMemsetAsync(bcnt, 0, (size_t)NB * 4, stream);
    bin_kernel<<<(E + BIN_CH - 1) / BIN_CH, 1024, 0, stream>>>(src, dst, bcnt, tmp, E, NB);
    bucket_kernel<<<NB, 256, 0, stream>>>(tmp, bcnt, dsq, rstart, rend, ssrc, N);

    // bf16/fp8 prep (also zeroes sentinel row N of yA/yB)
    int tot64 = N * 64;
    prep_kernel<<<(tot64 + 255) / 256, 256, 0, stream>>>(signal, dsq, X0b, yA, yB, tot64);
    wconv_kernel<<<(32768 + 255) / 256, 256, 0, stream>>>(W, Wb, 32768);

    int pullBlocks = (N + 3) / 4;
    pull_combine_kernel<<<pullBlocks, 256, 0, stream>>>(yA, rstart, rend, ssrc, dsq,
                                                        X0b, X0b, lam, X1b, yB, N, 1);
    pull_combine_kernel<<<pullBlocks, 256, 0, stream>>>(yB, rstart, rend, ssrc, dsq,
                                                        X1b, X0b, lam, X2b, yA, N, 2);
    pull_combine_kernel<<<pullBlocks, 256, 0, stream>>>(yA, rstart, rend, ssrc, dsq,
                                                        X2b, X1b, lam, X3b, nullptr, N, 2);

    // out = b + [X0|X1|X2|X3] @ W^T   (bf16 MFMA, fp32 accum)
    mfma_gemm_kernel<<<(N + 127) / 128, 256, 0, stream>>>(
        (const unsigned short*)X0b, (const unsigned short*)X1b,
        (const unsigned short*)X2b, (const unsigned short*)X3b,
        (const unsigned short*)Wb, bias, out, N);
}

// Round 16
// 368.681 us; speedup vs baseline: 1.2532x; 1.2532x over previous
//
#include <hip/hip_runtime.h>

#define FEAT 128
#define YS 8.0f     // fp8 encode scale for y = dsq*X
#define YIS 0.125f  // 1/YS
#define BSHIFT 8    // 256 nodes per bucket
#define NBMAX 512
#define BIN_CH 8192
#define CAP 16384   // edges per bucket: mean ~8184 + pad ~1920, 6-sigma safe

typedef __attribute__((ext_vector_type(8))) short bf16x8;
typedef __attribute__((ext_vector_type(4))) float f32x4;
typedef __attribute__((ext_vector_type(4))) int i32x4;
typedef __attribute__((ext_vector_type(2))) float f32x2;

__device__ __forceinline__ float2 upk_bf2(unsigned int p) {
    union { unsigned int u; float f; } a, b;
    a.u = p << 16;
    b.u = p & 0xffff0000u;
    return make_float2(a.f, b.f);
}
__device__ __forceinline__ unsigned short f2bf(float f) {
    union { float f; unsigned int u; } v;
    v.f = f;
    unsigned int b = v.u + 0x7fffu + ((v.u >> 16) & 1u);
    return (unsigned short)(b >> 16);
}
__device__ __forceinline__ unsigned int pk_bf2(float x, float y) {
    return (unsigned int)f2bf(x) | ((unsigned int)f2bf(y) << 16);
}

// ---- Phase A: bin edges by dst bucket into fixed-capacity regions --------
// Plain stores: the per-bucket runs NEED L2 write-coalescing (NT here was a
// 3x regression in round 15: WRITE_SIZE 45->130 MB).
__global__ __launch_bounds__(1024) void bin_kernel(const int* __restrict__ src,
                                                   const int* __restrict__ dst,
                                                   int* __restrict__ bcnt,
                                                   unsigned int* __restrict__ tmp,
                                                   int E, int NB) {
    __shared__ int cnt[NBMAX];
    __shared__ int base[NBMAX];
    int t = threadIdx.x;
    for (int i = t; i < NB; i += 1024) cnt[i] = 0;
    __syncthreads();
    int start = blockIdx.x * BIN_CH;
    int n = E - start;
    if (n > BIN_CH) n = BIN_CH;
    for (int k = t; k < n; k += 1024) atomicAdd(&cnt[dst[start + k] >> BSHIFT], 1);
    __syncthreads();
    for (int i = t; i < NB; i += 1024) {
        int c = cnt[i];
        base[i] = c ? atomicAdd(&bcnt[i], c) : 0;
        cnt[i] = 0;
    }
    __syncthreads();
    for (int k = t; k < n; k += 1024) {
        int s = src[start + k], d = dst[start + k];
        int b = d >> BSHIFT;
        int off = atomicAdd(&cnt[b], 1);
        tmp[(size_t)b * CAP + base[b] + off] =
            ((unsigned int)(d & 255) << 24) | (unsigned int)s;
    }
}

// ---- Phase B: per-bucket LDS degree count + scan + scatter ---------------
// Pads each node's edge list to a multiple of 16 with sentinel src = N.
__global__ __launch_bounds__(256) void bucket_kernel(
    const unsigned int* __restrict__ tmp, const int* __restrict__ bcnt,
    float* __restrict__ dsq, int* __restrict__ rstart, int* __restrict__ rend,
    int* __restrict__ ssrc, int N) {
    __shared__ int ldeg[256];
    __shared__ int lofs[256];
    int b = blockIdx.x;
    int t = threadIdx.x;
    int cnt = bcnt[b];
    ldeg[t] = 0;
    __syncthreads();
    const unsigned int* tp = tmp + (size_t)b * CAP;
    for (int e = t; e < cnt; e += 256) atomicAdd(&ldeg[tp[e] >> 24], 1);
    __syncthreads();
    int node = (b << BSHIFT) + t;
    int v = 0, pv = 0;
    if (node < N) {
        v = ldeg[t];
        pv = (v + 15) & ~15;
    }
    lofs[t] = pv;
    __syncthreads();
    for (int off = 1; off < 256; off <<= 1) {
        int add = (t >= off) ? lofs[t - off] : 0;
        __syncthreads();
        lofs[t] += add;
        __syncthreads();
    }
    int myStart = lofs[t] - pv;
    if (node < N) {
        dsq[node] = rsqrtf((float)(v < 1 ? 1 : v));
        rstart[node] = b * CAP + myStart;
        rend[node] = b * CAP + lofs[t];
    }
    ldeg[t] = myStart;
    __syncthreads();
    int* sp = ssrc + (size_t)b * CAP;
    for (int e = t; e < cnt; e += 256) {
        unsigned int p = tp[e];
        int dl = p >> 24;
        int pos = atomicAdd(&ldeg[dl], 1);
        sp[pos] = (int)(p & 0xFFFFFFu);
    }
    __syncthreads();
    if (node < N) {
        for (int p = myStart + v; p < myStart + pv; p++) sp[p] = N;
    }
}

// ---- prep: X0b = bf16(signal), y0 = fp8(YS * dsq * signal) --------------
__global__ void prep_kernel(const float* __restrict__ signal, const float* __restrict__ dsq,
                            unsigned int* __restrict__ X0b, unsigned short* __restrict__ y0,
                            unsigned short* __restrict__ y1, int total /* N*64 */) {
    int t = blockIdx.x * blockDim.x + threadIdx.x;
    if (t < 64) {
        y0[total + t] = 0;
        y1[total + t] = 0;
    }
    if (t >= total) return;
    int node = t >> 6;
    f32x2 v = __builtin_nontemporal_load((const f32x2*)signal + t);
    float ds = dsq[node];
    __builtin_nontemporal_store(pk_bf2(v[0], v[1]), X0b + t);
    int p = __builtin_amdgcn_cvt_pk_fp8_f32(v[0] * ds * YS, v[1] * ds * YS, 0, false);
    y0[t] = (unsigned short)p;
}

// ---- W -> fragment-major bf16 layout (1 KB burst per GEMM B-load) --------
__global__ void wconv_kernel(const float* __restrict__ W, unsigned int* __restrict__ Wb2,
                             int total /* 32768 */) {
    int u = blockIdx.x * blockDim.x + threadIdx.x;
    if (u >= total) return;
    int e2 = u & 3;
    int l15 = (u >> 2) & 15;
    int kg = (u >> 6) & 3;
    int kq = (u >> 8) & 3;
    int chunk = (u >> 10) & 3;
    int nt = (u >> 12) & 7;
    int col = nt * 16 + l15;
    int k = chunk * 128 + kq * 32 + kg * 8 + e2 * 2;
    float2 v = ((const float2*)W)[col * 256 + (k >> 1)];
    Wb2[u] = pk_bf2(v.x, v.y);
}

// ---- Fused pull + Chebyshev combine (fp8 gather, bf16 state) -------------
// 1 node/wave, unroll-16; NT hints on pure streams so L2 retains y8.
__global__ __launch_bounds__(256) void pull_combine_kernel(
    const unsigned short* __restrict__ y8, const int* __restrict__ rstart,
    const int* __restrict__ rend, const int* __restrict__ ssrc,
    const float* __restrict__ dsq, const unsigned int* __restrict__ xprev,
    const unsigned int* __restrict__ xpp, const float* __restrict__ lam,
    unsigned int* __restrict__ Xout, unsigned short* __restrict__ yout,
    int N, int mode) {
    int node = (blockIdx.x << 2) + (threadIdx.x >> 6);
    if (node >= N) return;
    int lane = threadIdx.x & 63;
    int i = __builtin_amdgcn_readfirstlane(rstart[node]);
    int end = __builtin_amdgcn_readfirstlane(rend[node]);
    float ax = 0.f, ay = 0.f;
    for (; i < end; i += 16) {
        i32x4 sa = __builtin_nontemporal_load((const i32x4*)(ssrc + i));
        i32x4 sb = __builtin_nontemporal_load((const i32x4*)(ssrc + i + 4));
        i32x4 sc = __builtin_nontemporal_load((const i32x4*)(ssrc + i + 8));
        i32x4 sd = __builtin_nontemporal_load((const i32x4*)(ssrc + i + 12));
        int s[16];
        s[0] = __builtin_amdgcn_readfirstlane(sa[0]);
        s[1] = __builtin_amdgcn_readfirstlane(sa[1]);
        s[2] = __builtin_amdgcn_readfirstlane(sa[2]);
        s[3] = __builtin_amdgcn_readfirstlane(sa[3]);
        s[4] = __builtin_amdgcn_readfirstlane(sb[0]);
        s[5] = __builtin_amdgcn_readfirstlane(sb[1]);
        s[6] = __builtin_amdgcn_readfirstlane(sb[2]);
        s[7] = __builtin_amdgcn_readfirstlane(sb[3]);
        s[8] = __builtin_amdgcn_readfirstlane(sc[0]);
        s[9] = __builtin_amdgcn_readfirstlane(sc[1]);
        s[10] = __builtin_amdgcn_readfirstlane(sc[2]);
        s[11] = __builtin_amdgcn_readfirstlane(sc[3]);
        s[12] = __builtin_amdgcn_readfirstlane(sd[0]);
        s[13] = __builtin_amdgcn_readfirstlane(sd[1]);
        s[14] = __builtin_amdgcn_readfirstlane(sd[2]);
        s[15] = __builtin_amdgcn_readfirstlane(sd[3]);
        unsigned int u[16];
#pragma unroll
        for (int j = 0; j < 16; j++) u[j] = y8[(size_t)s[j] * 64 + lane];
#pragma unroll
        for (int j = 0; j < 16; j++) {
            auto f = __builtin_amdgcn_cvt_pk_f32_fp8((int)u[j], false);
            ax += f[0];
            ay += f[1];
        }
    }
    float r = 2.0f / lam[0];
    float ds = dsq[node];
    size_t idx = (size_t)node * 64 + lane;
    float2 xp = upk_bf2(__builtin_nontemporal_load(xprev + idx));
    float rx, ry;
    if (mode == 1) {
        float alpha = -r * ds * YIS, beta = r - 1.0f;
        rx = alpha * ax + beta * xp.x;
        ry = alpha * ay + beta * xp.y;
    } else {
        float alpha = -2.0f * r * ds * YIS, beta = 2.0f * (r - 1.0f);
        float2 xq = upk_bf2(__builtin_nontemporal_load(xpp + idx));
        rx = alpha * ax + beta * xp.x - xq.x;
        ry = alpha * ay + beta * xp.y - xq.y;
    }
    __builtin_nontemporal_store(pk_bf2(rx, ry), Xout + idx);
    if (yout) {
        int p = __builtin_amdgcn_cvt_pk_fp8_f32(rx * ds * YS, ry * ds * YS, 0, false);
        __builtin_nontemporal_store((unsigned short)p, yout + idx);
    }
}

// ---- MFMA bf16 epilogue GEMM (fragment-major B, NT A-stream) -------------
__global__ __launch_bounds__(256, 4) void mfma_gemm_kernel(
    const unsigned short* __restrict__ X0, const unsigned short* __restrict__ X1,
    const unsigned short* __restrict__ X2, const unsigned short* __restrict__ X3,
    const unsigned short* __restrict__ Wb2, const float* __restrict__ bias,
    float* __restrict__ out, int M) {
    int tid = threadIdx.x;
    int lane = tid & 63;
    int w = tid >> 6;
    int m0 = blockIdx.x * 128 + w * 32;
    int l15 = lane & 15;
    int kg = lane >> 4;

    f32x4 acc[2][8];
#pragma unroll
    for (int rg = 0; rg < 2; rg++)
#pragma unroll
        for (int nt = 0; nt < 8; nt++) acc[rg][nt] = (f32x4)(0.f);

    const unsigned short* Xs[4] = {X0, X1, X2, X3};
    int arow[2];
#pragma unroll
    for (int rg = 0; rg < 2; rg++) {
        int r = m0 + rg * 16 + l15;
        arow[rg] = r < M ? r : M - 1;
    }
    const unsigned short* wlane = Wb2 + (kg * 16 + l15) * 8;

#pragma unroll
    for (int chunk = 0; chunk < 4; ++chunk) {
        const unsigned short* A = Xs[chunk];
#pragma unroll
        for (int kq = 0; kq < 4; kq++) {
            bf16x8 af[2];
#pragma unroll
            for (int rg = 0; rg < 2; rg++)
                af[rg] = __builtin_nontemporal_load(
                    (const bf16x8*)(A + (size_t)arow[rg] * 128 + kq * 32 + kg * 8));
#pragma unroll
            for (int nt = 0; nt < 8; nt++) {
                bf16x8 bf = *(const bf16x8*)(wlane + nt * 8192 + chunk * 2048 + kq * 512);
#pragma unroll
                for (int rg = 0; rg < 2; rg++)
                    acc[rg][nt] = __builtin_amdgcn_mfma_f32_16x16x32_bf16(af[rg], bf,
                                                                          acc[rg][nt], 0, 0, 0);
            }
        }
    }
#pragma unroll
    for (int nt = 0; nt < 8; nt++) {
        int col = nt * 16 + l15;
        float bb = bias[col];
#pragma unroll
        for (int rg = 0; rg < 2; rg++) {
#pragma unroll
            for (int r = 0; r < 4; r++) {
                int row = m0 + rg * 16 + kg * 4 + r;
                if (row < M)
                    __builtin_nontemporal_store(acc[rg][nt][r] + bb,
                                                out + (size_t)row * 128 + col);
            }
        }
    }
}

extern "C" void kernel_launch(void* const* d_in, const int* in_sizes, int n_in,
                              void* d_out, int out_size, void* d_ws, size_t ws_size,
                              hipStream_t stream) {
    const float* signal = (const float*)d_in[0];
    const int* src = (const int*)d_in[1];
    const int* dst = (const int*)d_in[2];
    const float* W = (const float*)d_in[3];
    const float* bias = (const float*)d_in[4];
    const float* lam = (const float*)d_in[5];
    int N = in_sizes[0] / FEAT;
    int E = in_sizes[1];
    float* out = (float*)d_out;
    int NB = (N + (1 << BSHIFT) - 1) >> BSHIFT;

    char* ws = (char*)d_ws;
    size_t off = 0;
    auto alloc = [&](size_t bytes) {
        char* p = ws + off;
        off += (bytes + 511) & ~(size_t)511;
        return p;
    };
    size_t nodeBf = (size_t)N * FEAT * 2;
    size_t nodeF8 = (size_t)(N + 1) * FEAT;
    size_t bucketBytes = (size_t)NB * CAP * 4;

    float* dsq = (float*)alloc((size_t)N * 4);
    int* bcnt = (int*)alloc((size_t)NB * 4);
    int* rstart = (int*)alloc((size_t)N * 4);
    int* rend = (int*)alloc((size_t)N * 4);
    int* ssrc = (int*)alloc(bucketBytes);
    unsigned int* tmp = (unsigned int*)alloc(bucketBytes);  // dead after bucket_kernel
    unsigned int* Wb = (unsigned int*)alloc((size_t)128 * 512 * 2);
    unsigned int* X0b = (unsigned int*)alloc(nodeBf);
    unsigned int* X1b = (unsigned int*)alloc(nodeBf);
    unsigned int* X2b = (unsigned int*)alloc(nodeBf);
    unsigned short* yA = (unsigned short*)alloc(nodeF8);
    unsigned short* yB = (unsigned short*)alloc(nodeF8);
    unsigned int* X3b = tmp;  // overlay: X3 written only after tmp is consumed

    // CSR build (bucket-local, no global node-granularity atomics)
    hipMemsetAsync(bcnt, 0, (size_t)NB * 4, stream);
    bin_kernel<<<(E + BIN_CH - 1) / BIN_CH, 1024, 0, stream>>>(src, dst, bcnt, tmp, E, NB);
    bucket_kernel<<<NB, 256, 0, stream>>>(tmp, bcnt, dsq, rstart, rend, ssrc, N);

    // bf16/fp8 prep (also zeroes sentinel row N of yA/yB)
    int tot64 = N * 64;
    prep_kernel<<<(tot64 + 255) / 256, 256, 0, stream>>>(signal, dsq, X0b, yA, yB, tot64);
    wconv_kernel<<<(32768 + 255) / 256, 256, 0, stream>>>(W, Wb, 32768);

    int pullBlocks = (N + 3) / 4;
    pull_combine_kernel<<<pullBlocks, 256, 0, stream>>>(yA, rstart, rend, ssrc, dsq,
                                                        X0b, X0b, lam, X1b, yB, N, 1);
    pull_combine_kernel<<<pullBlocks, 256, 0, stream>>>(yB, rstart, rend, ssrc, dsq,
                                                        X1b, X0b, lam, X2b, yA, N, 2);
    pull_combine_kernel<<<pullBlocks, 256, 0, stream>>>(yA, rstart, rend, ssrc, dsq,
                                                        X2b, X1b, lam, X3b, nullptr, N, 2);

    // out = b + [X0|X1|X2|X3] @ W^T   (bf16 MFMA, fp32 accum)
    mfma_gemm_kernel<<<(N + 127) / 128, 256, 0, stream>>>(
        (const unsigned short*)X0b, (const unsigned short*)X1b,
        (const unsigned short*)X2b, (const unsigned short*)X3b,
        (const unsigned short*)Wb, bias, out, N);
}

// Round 17
// 344.007 us; speedup vs baseline: 1.3430x; 1.0717x over previous
//
#include <hip/hip_runtime.h>

#define FEAT 128
#define YS 8.0f     // fp8 encode scale for y = dsq*X
#define YIS 0.125f  // 1/YS
#define BSHIFT 8    // 256 nodes per bucket
#define NBMAX 512
#define BIN_CH 8192
#define CAP 16384   // edges per bucket: mean ~8184 + pad ~1920, 6-sigma safe

typedef __attribute__((ext_vector_type(8))) short bf16x8;
typedef __attribute__((ext_vector_type(4))) float f32x4;

__device__ __forceinline__ float2 upk_bf2(unsigned int p) {
    union { unsigned int u; float f; } a, b;
    a.u = p << 16;
    b.u = p & 0xffff0000u;
    return make_float2(a.f, b.f);
}
__device__ __forceinline__ unsigned short f2bf(float f) {
    union { float f; unsigned int u; } v;
    v.f = f;
    unsigned int b = v.u + 0x7fffu + ((v.u >> 16) & 1u);
    return (unsigned short)(b >> 16);
}
__device__ __forceinline__ unsigned int pk_bf2(float x, float y) {
    return (unsigned int)f2bf(x) | ((unsigned int)f2bf(y) << 16);
}

// ---- Phase A: bin edges by dst bucket into fixed-capacity regions --------
// Plain stores: the per-bucket runs NEED L2 write-coalescing (NT here was a
// 3x regression: WRITE_SIZE 45->130 MB). Same for A-loads in the GEMM
// (NT there: FETCH 51->77 MB). No NT anywhere — all hot accesses rely on
// line reuse that NT discards.
__global__ __launch_bounds__(1024) void bin_kernel(const int* __restrict__ src,
                                                   const int* __restrict__ dst,
                                                   int* __restrict__ bcnt,
                                                   unsigned int* __restrict__ tmp,
                                                   int E, int NB) {
    __shared__ int cnt[NBMAX];
    __shared__ int base[NBMAX];
    int t = threadIdx.x;
    for (int i = t; i < NB; i += 1024) cnt[i] = 0;
    __syncthreads();
    int start = blockIdx.x * BIN_CH;
    int n = E - start;
    if (n > BIN_CH) n = BIN_CH;
    for (int k = t; k < n; k += 1024) atomicAdd(&cnt[dst[start + k] >> BSHIFT], 1);
    __syncthreads();
    for (int i = t; i < NB; i += 1024) {
        int c = cnt[i];
        base[i] = c ? atomicAdd(&bcnt[i], c) : 0;
        cnt[i] = 0;
    }
    __syncthreads();
    for (int k = t; k < n; k += 1024) {
        int s = src[start + k], d = dst[start + k];
        int b = d >> BSHIFT;
        int off = atomicAdd(&cnt[b], 1);
        tmp[(size_t)b * CAP + base[b] + off] =
            ((unsigned int)(d & 255) << 24) | (unsigned int)s;
    }
}

// ---- Phase B: per-bucket LDS degree count + scan + scatter ---------------
// Pads each node's edge list to a multiple of 16 with sentinel src = N.
__global__ __launch_bounds__(256) void bucket_kernel(
    const unsigned int* __restrict__ tmp, const int* __restrict__ bcnt,
    float* __restrict__ dsq, int* __restrict__ rstart, int* __restrict__ rend,
    int* __restrict__ ssrc, int N) {
    __shared__ int ldeg[256];
    __shared__ int lofs[256];
    int b = blockIdx.x;
    int t = threadIdx.x;
    int cnt = bcnt[b];
    ldeg[t] = 0;
    __syncthreads();
    const unsigned int* tp = tmp + (size_t)b * CAP;
    for (int e = t; e < cnt; e += 256) atomicAdd(&ldeg[tp[e] >> 24], 1);
    __syncthreads();
    int node = (b << BSHIFT) + t;
    int v = 0, pv = 0;
    if (node < N) {
        v = ldeg[t];
        pv = (v + 15) & ~15;
    }
    lofs[t] = pv;
    __syncthreads();
    for (int off = 1; off < 256; off <<= 1) {
        int add = (t >= off) ? lofs[t - off] : 0;
        __syncthreads();
        lofs[t] += add;
        __syncthreads();
    }
    int myStart = lofs[t] - pv;
    if (node < N) {
        dsq[node] = rsqrtf((float)(v < 1 ? 1 : v));
        rstart[node] = b * CAP + myStart;
        rend[node] = b * CAP + lofs[t];
    }
    ldeg[t] = myStart;
    __syncthreads();
    int* sp = ssrc + (size_t)b * CAP;
    for (int e = t; e < cnt; e += 256) {
        unsigned int p = tp[e];
        int dl = p >> 24;
        int pos = atomicAdd(&ldeg[dl], 1);
        sp[pos] = (int)(p & 0xFFFFFFu);
    }
    __syncthreads();
    if (node < N) {
        for (int p = myStart + v; p < myStart + pv; p++) sp[p] = N;
    }
}

// ---- prep: X0b = bf16(signal), y0 = fp8(YS * dsq * signal) --------------
__global__ void prep_kernel(const float* __restrict__ signal, const float* __restrict__ dsq,
                            unsigned int* __restrict__ X0b, unsigned short* __restrict__ y0,
                            unsigned short* __restrict__ y1, int total /* N*64 */) {
    int t = blockIdx.x * blockDim.x + threadIdx.x;
    if (t < 64) {
        y0[total + t] = 0;
        y1[total + t] = 0;
    }
    if (t >= total) return;
    int node = t >> 6;
    float2 v = ((const float2*)signal)[t];
    float ds = dsq[node];
    X0b[t] = pk_bf2(v.x, v.y);
    int p = __builtin_amdgcn_cvt_pk_fp8_f32(v.x * ds * YS, v.y * ds * YS, 0, false);
    y0[t] = (unsigned short)p;
}

// ---- W -> fragment-major bf16 layout (1 KB burst per GEMM B-load) --------
__global__ void wconv_kernel(const float* __restrict__ W, unsigned int* __restrict__ Wb2,
                             int total /* 32768 */) {
    int u = blockIdx.x * blockDim.x + threadIdx.x;
    if (u >= total) return;
    int e2 = u & 3;
    int l15 = (u >> 2) & 15;
    int kg = (u >> 6) & 3;
    int kq = (u >> 8) & 3;
    int chunk = (u >> 10) & 3;
    int nt = (u >> 12) & 7;
    int col = nt * 16 + l15;
    int k = chunk * 128 + kq * 32 + kg * 8 + e2 * 2;
    float2 v = ((const float2*)W)[col * 256 + (k >> 1)];
    Wb2[u] = pk_bf2(v.x, v.y);
}

// ---- Fused pull + Chebyshev combine (fp8 gather, bf16 state) -------------
// 1 node/wave, unroll-16 over padded edge lists.
__global__ __launch_bounds__(256) void pull_combine_kernel(
    const unsigned short* __restrict__ y8, const int* __restrict__ rstart,
    const int* __restrict__ rend, const int* __restrict__ ssrc,
    const float* __restrict__ dsq, const unsigned int* __restrict__ xprev,
    const unsigned int* __restrict__ xpp, const float* __restrict__ lam,
    unsigned int* __restrict__ Xout, unsigned short* __restrict__ yout,
    int N, int mode) {
    int node = (blockIdx.x << 2) + (threadIdx.x >> 6);
    if (node >= N) return;
    int lane = threadIdx.x & 63;
    int i = __builtin_amdgcn_readfirstlane(rstart[node]);
    int end = __builtin_amdgcn_readfirstlane(rend[node]);
    float ax = 0.f, ay = 0.f;
    for (; i < end; i += 16) {
        int4 sa = *(const int4*)(ssrc + i);
        int4 sb = *(const int4*)(ssrc + i + 4);
        int4 sc = *(const int4*)(ssrc + i + 8);
        int4 sd = *(const int4*)(ssrc + i + 12);
        int s[16];
        s[0] = __builtin_amdgcn_readfirstlane(sa.x);
        s[1] = __builtin_amdgcn_readfirstlane(sa.y);
        s[2] = __builtin_amdgcn_readfirstlane(sa.z);
        s[3] = __builtin_amdgcn_readfirstlane(sa.w);
        s[4] = __builtin_amdgcn_readfirstlane(sb.x);
        s[5] = __builtin_amdgcn_readfirstlane(sb.y);
        s[6] = __builtin_amdgcn_readfirstlane(sb.z);
        s[7] = __builtin_amdgcn_readfirstlane(sb.w);
        s[8] = __builtin_amdgcn_readfirstlane(sc.x);
        s[9] = __builtin_amdgcn_readfirstlane(sc.y);
        s[10] = __builtin_amdgcn_readfirstlane(sc.z);
        s[11] = __builtin_amdgcn_readfirstlane(sc.w);
        s[12] = __builtin_amdgcn_readfirstlane(sd.x);
        s[13] = __builtin_amdgcn_readfirstlane(sd.y);
        s[14] = __builtin_amdgcn_readfirstlane(sd.z);
        s[15] = __builtin_amdgcn_readfirstlane(sd.w);
        unsigned int u[16];
#pragma unroll
        for (int j = 0; j < 16; j++) u[j] = y8[(size_t)s[j] * 64 + lane];
#pragma unroll
        for (int j = 0; j < 16; j++) {
            auto f = __builtin_amdgcn_cvt_pk_f32_fp8((int)u[j], false);
            ax += f[0];
            ay += f[1];
        }
    }
    float r = 2.0f / lam[0];
    float ds = dsq[node];
    size_t idx = (size_t)node * 64 + lane;
    float2 xp = upk_bf2(xprev[idx]);
    float rx, ry;
    if (mode == 1) {
        float alpha = -r * ds * YIS, beta = r - 1.0f;
        rx = alpha * ax + beta * xp.x;
        ry = alpha * ay + beta * xp.y;
    } else {
        float alpha = -2.0f * r * ds * YIS, beta = 2.0f * (r - 1.0f);
        float2 xq = upk_bf2(xpp[idx]);
        rx = alpha * ax + beta * xp.x - xq.x;
        ry = alpha * ay + beta * xp.y - xq.y;
    }
    Xout[idx] = pk_bf2(rx, ry);
    if (yout) {
        int p = __builtin_amdgcn_cvt_pk_fp8_f32(rx * ds * YS, ry * ds * YS, 0, false);
        yout[idx] = (unsigned short)p;
    }
}

// ---- MFMA bf16 epilogue GEMM (fragment-major B) --------------------------
__global__ __launch_bounds__(256, 4) void mfma_gemm_kernel(
    const unsigned short* __restrict__ X0, const unsigned short* __restrict__ X1,
    const unsigned short* __restrict__ X2, const unsigned short* __restrict__ X3,
    const unsigned short* __restrict__ Wb2, const float* __restrict__ bias,
    float* __restrict__ out, int M) {
    int tid = threadIdx.x;
    int lane = tid & 63;
    int w = tid >> 6;
    int m0 = blockIdx.x * 128 + w * 32;
    int l15 = lane & 15;
    int kg = lane >> 4;

    f32x4 acc[2][8];
#pragma unroll
    for (int rg = 0; rg < 2; rg++)
#pragma unroll
        for (int nt = 0; nt < 8; nt++) acc[rg][nt] = (f32x4)(0.f);

    const unsigned short* Xs[4] = {X0, X1, X2, X3};
    int arow[2];
#pragma unroll
    for (int rg = 0; rg < 2; rg++) {
        int r = m0 + rg * 16 + l15;
        arow[rg] = r < M ? r : M - 1;
    }
    const unsigned short* wlane = Wb2 + (kg * 16 + l15) * 8;

#pragma unroll
    for (int chunk = 0; chunk < 4; ++chunk) {
        const unsigned short* A = Xs[chunk];
#pragma unroll
        for (int kq = 0; kq < 4; kq++) {
            bf16x8 af[2];
#pragma unroll
            for (int rg = 0; rg < 2; rg++)
                af[rg] = *(const bf16x8*)(A + (size_t)arow[rg] * 128 + kq * 32 + kg * 8);
#pragma unroll
            for (int nt = 0; nt < 8; nt++) {
                bf16x8 bf = *(const bf16x8*)(wlane + nt * 8192 + chunk * 2048 + kq * 512);
#pragma unroll
                for (int rg = 0; rg < 2; rg++)
                    acc[rg][nt] = __builtin_amdgcn_mfma_f32_16x16x32_bf16(af[rg], bf,
                                                                          acc[rg][nt], 0, 0, 0);
            }
        }
    }
#pragma unroll
    for (int nt = 0; nt < 8; nt++) {
        int col = nt * 16 + l15;
        float bb = bias[col];
#pragma unroll
        for (int rg = 0; rg < 2; rg++) {
#pragma unroll
            for (int r = 0; r < 4; r++) {
                int row = m0 + rg * 16 + kg * 4 + r;
                if (row < M) out[(size_t)row * 128 + col] = acc[rg][nt][r] + bb;
            }
        }
    }
}

extern "C" void kernel_launch(void* const* d_in, const int* in_sizes, int n_in,
                              void* d_out, int out_size, void* d_ws, size_t ws_size,
                              hipStream_t stream) {
    const float* signal = (const float*)d_in[0];
    const int* src = (const int*)d_in[1];
    const int* dst = (const int*)d_in[2];
    const float* W = (const float*)d_in[3];
    const float* bias = (const float*)d_in[4];
    const float* lam = (const float*)d_in[5];
    int N = in_sizes[0] / FEAT;
    int E = in_sizes[1];
    float* out = (float*)d_out;
    int NB = (N + (1 << BSHIFT) - 1) >> BSHIFT;

    char* ws = (char*)d_ws;
    size_t off = 0;
    auto alloc = [&](size_t bytes) {
        char* p = ws + off;
        off += (bytes + 511) & ~(size_t)511;
        return p;
    };
    size_t nodeBf = (size_t)N * FEAT * 2;
    size_t nodeF8 = (size_t)(N + 1) * FEAT;
    size_t bucketBytes = (size_t)NB * CAP * 4;

    float* dsq = (float*)alloc((size_t)N * 4);
    int* bcnt = (int*)alloc((size_t)NB * 4);
    int* rstart = (int*)alloc((size_t)N * 4);
    int* rend = (int*)alloc((size_t)N * 4);
    int* ssrc = (int*)alloc(bucketBytes);
    unsigned int* tmp = (unsigned int*)alloc(bucketBytes);  // dead after bucket_kernel
    unsigned int* Wb = (unsigned int*)alloc((size_t)128 * 512 * 2);
    unsigned int* X0b = (unsigned int*)alloc(nodeBf);
    unsigned int* X1b = (unsigned int*)alloc(nodeBf);
    unsigned int* X2b = (unsigned int*)alloc(nodeBf);
    unsigned short* yA = (unsigned short*)alloc(nodeF8);
    unsigned short* yB = (unsigned short*)alloc(nodeF8);
    unsigned int* X3b = tmp;  // overlay: X3 written only after tmp is consumed

    // CSR build (bucket-local, no global node-granularity atomics)
    hipMemsetAsync(bcnt, 0, (size_t)NB * 4, stream);
    bin_kernel<<<(E + BIN_CH - 1) / BIN_CH, 1024, 0, stream>>>(src, dst, bcnt, tmp, E, NB);
    bucket_kernel<<<NB, 256, 0, stream>>>(tmp, bcnt, dsq, rstart, rend, ssrc, N);

    // bf16/fp8 prep (also zeroes sentinel row N of yA/yB)
    int tot64 = N * 64;
    prep_kernel<<<(tot64 + 255) / 256, 256, 0, stream>>>(signal, dsq, X0b, yA, yB, tot64);
    wconv_kernel<<<(32768 + 255) / 256, 256, 0, stream>>>(W, Wb, 32768);

    int pullBlocks = (N + 3) / 4;
    pull_combine_kernel<<<pullBlocks, 256, 0, stream>>>(yA, rstart, rend, ssrc, dsq,
                                                        X0b, X0b, lam, X1b, yB, N, 1);
    pull_combine_kernel<<<pullBlocks, 256, 0, stream>>>(yB, rstart, rend, ssrc, dsq,
                                                        X1b, X0b, lam, X2b, yA, N, 2);
    pull_combine_kernel<<<pullBlocks, 256, 0, stream>>>(yA, rstart, rend, ssrc, dsq,
                                                        X2b, X1b, lam, X3b, nullptr, N, 2);

    // out = b + [X0|X1|X2|X3] @ W^T   (bf16 MFMA, fp32 accum)
    mfma_gemm_kernel<<<(N + 127) / 128, 256, 0, stream>>>(
        (const unsigned short*)X0b, (const unsigned short*)X1b,
        (const unsigned short*)X2b, (const unsigned short*)X3b,
        (const unsigned short*)Wb, bias, out, N);
}

// Round 18
// 336.977 us; speedup vs baseline: 1.3711x; 1.0209x over previous
//
#include <hip/hip_runtime.h>

#define FEAT 128
#define YS 8.0f     // fp8 encode scale for y = dsq*X
#define YIS 0.125f  // 1/YS
#define BSHIFT 8    // 256 nodes per bucket
#define NBMAX 512
#define BIN_CH 8192
#define CAP 16384   // edges per bucket: mean ~8184 + pad ~1920, 6-sigma safe

typedef __attribute__((ext_vector_type(8))) short bf16x8;
typedef __attribute__((ext_vector_type(4))) float f32x4;

__device__ __forceinline__ float2 upk_bf2(unsigned int p) {
    union { unsigned int u; float f; } a, b;
    a.u = p << 16;
    b.u = p & 0xffff0000u;
    return make_float2(a.f, b.f);
}
__device__ __forceinline__ unsigned short f2bf(float f) {
    union { float f; unsigned int u; } v;
    v.f = f;
    unsigned int b = v.u + 0x7fffu + ((v.u >> 16) & 1u);
    return (unsigned short)(b >> 16);
}
__device__ __forceinline__ unsigned int pk_bf2(float x, float y) {
    return (unsigned int)f2bf(x) | ((unsigned int)f2bf(y) << 16);
}

// ---- Phase A: bin edges by dst bucket into fixed-capacity regions --------
// Plain stores: per-bucket runs NEED L2 write-coalescing (NT was 3x worse).
__global__ __launch_bounds__(1024) void bin_kernel(const int* __restrict__ src,
                                                   const int* __restrict__ dst,
                                                   int* __restrict__ bcnt,
                                                   unsigned int* __restrict__ tmp,
                                                   int E, int NB) {
    __shared__ int cnt[NBMAX];
    __shared__ int base[NBMAX];
    int t = threadIdx.x;
    for (int i = t; i < NB; i += 1024) cnt[i] = 0;
    __syncthreads();
    int start = blockIdx.x * BIN_CH;
    int n = E - start;
    if (n > BIN_CH) n = BIN_CH;
    for (int k = t; k < n; k += 1024) atomicAdd(&cnt[dst[start + k] >> BSHIFT], 1);
    __syncthreads();
    for (int i = t; i < NB; i += 1024) {
        int c = cnt[i];
        base[i] = c ? atomicAdd(&bcnt[i], c) : 0;
        cnt[i] = 0;
    }
    __syncthreads();
    for (int k = t; k < n; k += 1024) {
        int s = src[start + k], d = dst[start + k];
        int b = d >> BSHIFT;
        int off = atomicAdd(&cnt[b], 1);
        tmp[(size_t)b * CAP + base[b] + off] =
            ((unsigned int)(d & 255) << 24) | (unsigned int)s;
    }
}

// ---- Phase B: per-bucket LDS degree count + scan + scatter ---------------
// Pads each node's edge list to a multiple of 16 with sentinel src = N.
__global__ __launch_bounds__(256) void bucket_kernel(
    const unsigned int* __restrict__ tmp, const int* __restrict__ bcnt,
    float* __restrict__ dsq, int* __restrict__ rstart, int* __restrict__ rend,
    int* __restrict__ ssrc, int N) {
    __shared__ int ldeg[256];
    __shared__ int lofs[256];
    int b = blockIdx.x;
    int t = threadIdx.x;
    int cnt = bcnt[b];
    ldeg[t] = 0;
    __syncthreads();
    const unsigned int* tp = tmp + (size_t)b * CAP;
    for (int e = t; e < cnt; e += 256) atomicAdd(&ldeg[tp[e] >> 24], 1);
    __syncthreads();
    int node = (b << BSHIFT) + t;
    int v = 0, pv = 0;
    if (node < N) {
        v = ldeg[t];
        pv = (v + 15) & ~15;
    }
    lofs[t] = pv;
    __syncthreads();
    for (int off = 1; off < 256; off <<= 1) {
        int add = (t >= off) ? lofs[t - off] : 0;
        __syncthreads();
        lofs[t] += add;
        __syncthreads();
    }
    int myStart = lofs[t] - pv;
    if (node < N) {
        dsq[node] = rsqrtf((float)(v < 1 ? 1 : v));
        rstart[node] = b * CAP + myStart;
        rend[node] = b * CAP + lofs[t];
    }
    ldeg[t] = myStart;
    __syncthreads();
    int* sp = ssrc + (size_t)b * CAP;
    for (int e = t; e < cnt; e += 256) {
        unsigned int p = tp[e];
        int dl = p >> 24;
        int pos = atomicAdd(&ldeg[dl], 1);
        sp[pos] = (int)(p & 0xFFFFFFu);
    }
    __syncthreads();
    if (node < N) {
        for (int p = myStart + v; p < myStart + pv; p++) sp[p] = N;
    }
}

// ---- prep: X0b = bf16(signal), y0 = fp8(YS * dsq * signal) --------------
__global__ void prep_kernel(const float* __restrict__ signal, const float* __restrict__ dsq,
                            unsigned int* __restrict__ X0b, unsigned short* __restrict__ y0,
                            unsigned short* __restrict__ y1, int total /* N*64 */) {
    int t = blockIdx.x * blockDim.x + threadIdx.x;
    if (t < 64) {
        y0[total + t] = 0;
        y1[total + t] = 0;
    }
    if (t >= total) return;
    int node = t >> 6;
    float2 v = ((const float2*)signal)[t];
    float ds = dsq[node];
    X0b[t] = pk_bf2(v.x, v.y);
    int p = __builtin_amdgcn_cvt_pk_fp8_f32(v.x * ds * YS, v.y * ds * YS, 0, false);
    y0[t] = (unsigned short)p;
}

// ---- W -> fragment-major bf16 layout (1 KB burst per GEMM B-load) --------
__global__ void wconv_kernel(const float* __restrict__ W, unsigned int* __restrict__ Wb2,
                             int total /* 32768 */) {
    int u = blockIdx.x * blockDim.x + threadIdx.x;
    if (u >= total) return;
    int e2 = u & 3;
    int l15 = (u >> 2) & 15;
    int kg = (u >> 6) & 3;
    int kq = (u >> 8) & 3;
    int chunk = (u >> 10) & 3;
    int nt = (u >> 12) & 7;
    int col = nt * 16 + l15;
    int k = chunk * 128 + kq * 32 + kg * 8 + e2 * 2;
    float2 v = ((const float2*)W)[col * 256 + (k >> 1)];
    Wb2[u] = pk_bf2(v.x, v.y);
}

// ---- Fused pull + Chebyshev combine (fp8 gather, bf16 state) -------------
// 1 node/wave, unroll-16 over padded edge lists.
// beta == 0 (lambda_max == 2 -> r == 1) is detected at runtime (wave-uniform)
// and skips the dead xprev stream: exact for finite inputs, general for any
// lambda.
__global__ __launch_bounds__(256) void pull_combine_kernel(
    const unsigned short* __restrict__ y8, const int* __restrict__ rstart,
    const int* __restrict__ rend, const int* __restrict__ ssrc,
    const float* __restrict__ dsq, const unsigned int* __restrict__ xprev,
    const unsigned int* __restrict__ xpp, const float* __restrict__ lam,
    unsigned int* __restrict__ Xout, unsigned short* __restrict__ yout,
    int N, int mode) {
    int node = (blockIdx.x << 2) + (threadIdx.x >> 6);
    if (node >= N) return;
    int lane = threadIdx.x & 63;
    int i = __builtin_amdgcn_readfirstlane(rstart[node]);
    int end = __builtin_amdgcn_readfirstlane(rend[node]);
    float ax = 0.f, ay = 0.f;
    for (; i < end; i += 16) {
        int4 sa = *(const int4*)(ssrc + i);
        int4 sb = *(const int4*)(ssrc + i + 4);
        int4 sc = *(const int4*)(ssrc + i + 8);
        int4 sd = *(const int4*)(ssrc + i + 12);
        int s[16];
        s[0] = __builtin_amdgcn_readfirstlane(sa.x);
        s[1] = __builtin_amdgcn_readfirstlane(sa.y);
        s[2] = __builtin_amdgcn_readfirstlane(sa.z);
        s[3] = __builtin_amdgcn_readfirstlane(sa.w);
        s[4] = __builtin_amdgcn_readfirstlane(sb.x);
        s[5] = __builtin_amdgcn_readfirstlane(sb.y);
        s[6] = __builtin_amdgcn_readfirstlane(sb.z);
        s[7] = __builtin_amdgcn_readfirstlane(sb.w);
        s[8] = __builtin_amdgcn_readfirstlane(sc.x);
        s[9] = __builtin_amdgcn_readfirstlane(sc.y);
        s[10] = __builtin_amdgcn_readfirstlane(sc.z);
        s[11] = __builtin_amdgcn_readfirstlane(sc.w);
        s[12] = __builtin_amdgcn_readfirstlane(sd.x);
        s[13] = __builtin_amdgcn_readfirstlane(sd.y);
        s[14] = __builtin_amdgcn_readfirstlane(sd.z);
        s[15] = __builtin_amdgcn_readfirstlane(sd.w);
        unsigned int u[16];
#pragma unroll
        for (int j = 0; j < 16; j++) u[j] = y8[(size_t)s[j] * 64 + lane];
#pragma unroll
        for (int j = 0; j < 16; j++) {
            auto f = __builtin_amdgcn_cvt_pk_f32_fp8((int)u[j], false);
            ax += f[0];
            ay += f[1];
        }
    }
    float r = 2.0f / lam[0];
    float ds = dsq[node];
    size_t idx = (size_t)node * 64 + lane;
    float alpha, beta;
    if (mode == 1) {
        alpha = -r * ds * YIS;
        beta = r - 1.0f;
    } else {
        alpha = -2.0f * r * ds * YIS;
        beta = 2.0f * (r - 1.0f);
    }
    float rx = alpha * ax, ry = alpha * ay;
    if (beta != 0.0f) {  // wave-uniform: skip dead xprev stream when r == 1
        float2 xp = upk_bf2(xprev[idx]);
        rx += beta * xp.x;
        ry += beta * xp.y;
    }
    if (mode != 1) {
        float2 xq = upk_bf2(xpp[idx]);
        rx -= xq.x;
        ry -= xq.y;
    }
    Xout[idx] = pk_bf2(rx, ry);
    if (yout) {
        int p = __builtin_amdgcn_cvt_pk_fp8_f32(rx * ds * YS, ry * ds * YS, 0, false);
        yout[idx] = (unsigned short)p;
    }
}

// ---- MFMA bf16 epilogue GEMM (fragment-major B) --------------------------
__global__ __launch_bounds__(256, 4) void mfma_gemm_kernel(
    const unsigned short* __restrict__ X0, const unsigned short* __restrict__ X1,
    const unsigned short* __restrict__ X2, const unsigned short* __restrict__ X3,
    const unsigned short* __restrict__ Wb2, const float* __restrict__ bias,
    float* __restrict__ out, int M) {
    int tid = threadIdx.x;
    int lane = tid & 63;
    int w = tid >> 6;
    int m0 = blockIdx.x * 128 + w * 32;
    int l15 = lane & 15;
    int kg = lane >> 4;

    f32x4 acc[2][8];
#pragma unroll
    for (int rg = 0; rg < 2; rg++)
#pragma unroll
        for (int nt = 0; nt < 8; nt++) acc[rg][nt] = (f32x4)(0.f);

    const unsigned short* Xs[4] = {X0, X1, X2, X3};
    int arow[2];
#pragma unroll
    for (int rg = 0; rg < 2; rg++) {
        int r = m0 + rg * 16 + l15;
        arow[rg] = r < M ? r : M - 1;
    }
    const unsigned short* wlane = Wb2 + (kg * 16 + l15) * 8;

#pragma unroll
    for (int chunk = 0; chunk < 4; ++chunk) {
        const unsigned short* A = Xs[chunk];
#pragma unroll
        for (int kq = 0; kq < 4; kq++) {
            bf16x8 af[2];
#pragma unroll
            for (int rg = 0; rg < 2; rg++)
                af[rg] = *(const bf16x8*)(A + (size_t)arow[rg] * 128 + kq * 32 + kg * 8);
#pragma unroll
            for (int nt = 0; nt < 8; nt++) {
                bf16x8 bf = *(const bf16x8*)(wlane + nt * 8192 + chunk * 2048 + kq * 512);
#pragma unroll
                for (int rg = 0; rg < 2; rg++)
                    acc[rg][nt] = __builtin_amdgcn_mfma_f32_16x16x32_bf16(af[rg], bf,
                                                                          acc[rg][nt], 0, 0, 0);
            }
        }
    }
#pragma unroll
    for (int nt = 0; nt < 8; nt++) {
        int col = nt * 16 + l15;
        float bb = bias[col];
#pragma unroll
        for (int rg = 0; rg < 2; rg++) {
#pragma unroll
            for (int r = 0; r < 4; r++) {
                int row = m0 + rg * 16 + kg * 4 + r;
                if (row < M) out[(size_t)row * 128 + col] = acc[rg][nt][r] + bb;
            }
        }
    }
}

extern "C" void kernel_launch(void* const* d_in, const int* in_sizes, int n_in,
                              void* d_out, int out_size, void* d_ws, size_t ws_size,
                              hipStream_t stream) {
    const float* signal = (const float*)d_in[0];
    const int* src = (const int*)d_in[1];
    const int* dst = (const int*)d_in[2];
    const float* W = (const float*)d_in[3];
    const float* bias = (const float*)d_in[4];
    const float* lam = (const float*)d_in[5];
    int N = in_sizes[0] / FEAT;
    int E = in_sizes[1];
    float* out = (float*)d_out;
    int NB = (N + (1 << BSHIFT) - 1) >> BSHIFT;

    char* ws = (char*)d_ws;
    size_t off = 0;
    auto alloc = [&](size_t bytes) {
        char* p = ws + off;
        off += (bytes + 511) & ~(size_t)511;
        return p;
    };
    size_t nodeBf = (size_t)N * FEAT * 2;
    size_t nodeF8 = (size_t)(N + 1) * FEAT;
    size_t bucketBytes = (size_t)NB * CAP * 4;

    float* dsq = (float*)alloc((size_t)N * 4);
    int* bcnt = (int*)alloc((size_t)NB * 4);
    int* rstart = (int*)alloc((size_t)N * 4);
    int* rend = (int*)alloc((size_t)N * 4);
    int* ssrc = (int*)alloc(bucketBytes);
    unsigned int* tmp = (unsigned int*)alloc(bucketBytes);  // dead after bucket_kernel
    unsigned int* Wb = (unsigned int*)alloc((size_t)128 * 512 * 2);
    unsigned int* X0b = (unsigned int*)alloc(nodeBf);
    unsigned int* X1b = (unsigned int*)alloc(nodeBf);
    unsigned int* X2b = (unsigned int*)alloc(nodeBf);
    unsigned short* yA = (unsigned short*)alloc(nodeF8);
    unsigned short* yB = (unsigned short*)alloc(nodeF8);
    unsigned int* X3b = tmp;  // overlay: X3 written only after tmp is consumed

    // CSR build (bucket-local, no global node-granularity atomics)
    hipMemsetAsync(bcnt, 0, (size_t)NB * 4, stream);
    bin_kernel<<<(E + BIN_CH - 1) / BIN_CH, 1024, 0, stream>>>(src, dst, bcnt, tmp, E, NB);
    bucket_kernel<<<NB, 256, 0, stream>>>(tmp, bcnt, dsq, rstart, rend, ssrc, N);

    // bf16/fp8 prep (also zeroes sentinel row N of yA/yB)
    int tot64 = N * 64;
    prep_kernel<<<(tot64 + 255) / 256, 256, 0, stream>>>(signal, dsq, X0b, yA, yB, tot64);
    wconv_kernel<<<(32768 + 255) / 256, 256, 0, stream>>>(W, Wb, 32768);

    int pullBlocks = (N + 3) / 4;
    pull_combine_kernel<<<pullBlocks, 256, 0, stream>>>(yA, rstart, rend, ssrc, dsq,
                                                        X0b, X0b, lam, X1b, yB, N, 1);
    pull_combine_kernel<<<pullBlocks, 256, 0, stream>>>(yB, rstart, rend, ssrc, dsq,
                                                        X1b, X0b, lam, X2b, yA, N, 2);
    pull_combine_kernel<<<pullBlocks, 256, 0, stream>>>(yA, rstart, rend, ssrc, dsq,
                                                        X2b, X1b, lam, X3b, nullptr, N, 2);

    // out = b + [X0|X1|X2|X3] @ W^T   (bf16 MFMA, fp32 accum)
    mfma_gemm_kernel<<<(N + 127) / 128, 256, 0, stream>>>(
        (const unsigned short*)X0b, (const unsigned short*)X1b,
        (const unsigned short*)X2b, (const unsigned short*)X3b,
        (const unsigned short*)Wb, bias, out, N);
}